// Round 5
// baseline (156.108 us; speedup 1.0000x reference)
//
#include <hip/hip_runtime.h>
#include <hip/hip_cooperative_groups.h>

namespace cg = cooperative_groups;

#define D0 1024
#define D1 512
#define D2 256
#define NROWSUM (D0 + D1)

typedef float f32x4 __attribute__((ext_vector_type(4)));

// Single fused cooperative kernel.
// Phase 1: rowsums of W0 (1024x512) and W1 (512x256) -> s[1536].
//   (pred[b,i] = avg[b]*rowsum(W)[i] because cur is a [B,1] broadcast, so the
//    per-layer state collapses to scalars (v, avg) per batch row.)
// Then each wave ISSUES its first x-row-pair loads (they stay in flight across
// the grid barrier — vmcnt only drains at use), grid.sync(), phase 2 iterates
// the scalar LIF dynamics per batch row with the exact-fixed-point early break.
__global__ __launch_bounds__(256, 4) void snn_fused(
    const float* __restrict__ x,
    const float* __restrict__ W0,
    const float* __restrict__ W1,
    const int*   __restrict__ ts_ptr,
    float* __restrict__ out,
    float* __restrict__ s,
    int B)
{
    const int lane = threadIdx.x & 63;
    const int wid  = threadIdx.x >> 6;
    const int gw   = blockIdx.x * 4 + wid;   // global wave id
    const int nw   = gridDim.x * 4;          // total waves

    // ---------------- phase 1: rowsums ----------------
    for (int row = gw; row < NROWSUM; row += nw) {
        const f32x4* base; int n4;
        if (row < D0) { base = (const f32x4*)(W0 + (size_t)row * D1);        n4 = D1 / 4; }
        else          { base = (const f32x4*)(W1 + (size_t)(row - D0) * D2); n4 = D2 / 4; }
        double acc = 0.0;
        for (int j = lane; j < n4; j += 64) {
            const f32x4 v = base[j];
            acc += ((double)v.x + (double)v.y) + ((double)v.z + (double)v.w);
        }
        #pragma unroll
        for (int off = 32; off >= 1; off >>= 1) acc += __shfl_xor(acc, off, 64);
        if (lane == 0) s[row] = (float)acc;
    }

    // ------- prefetch first x pair; loads complete across the barrier -------
    const int P = (B + 1) >> 1;   // row pairs
    const int pair0 = gw;
    f32x4 xa[4], xb[4];
    int b0 = 0, b1 = 0; bool has2 = false;
    if (pair0 < P) {
        b0 = pair0 * 2; has2 = (b0 + 1) < B; b1 = has2 ? b0 + 1 : b0;
        const f32x4* xv0 = (const f32x4*)(x + (size_t)b0 * D0);
        const f32x4* xv1 = (const f32x4*)(x + (size_t)b1 * D0);
        #pragma unroll
        for (int k = 0; k < 4; ++k) xa[k] = xv0[k * 64 + lane];
        #pragma unroll
        for (int k = 0; k < 4; ++k) xb[k] = xv1[k * 64 + lane];
    }

    __threadfence();            // device-scope release of s
    cg::this_grid().sync();     // all rowsums visible grid-wide

    // ---------------- phase 2: LIF iteration ----------------
    const f32x4* sv = (const f32x4*)s;
    f32x4 s0k[4], s1k[2];
    #pragma unroll
    for (int k = 0; k < 4; ++k) s0k[k] = sv[k * 64 + lane];
    #pragma unroll
    for (int k = 0; k < 2; ++k) s1k[k] = sv[D0 / 4 + k * 64 + lane];
    const int TS = *ts_ptr;

    for (int pair = pair0; pair < P; pair += nw) {
        if (pair != pair0) {
            b0 = pair * 2; has2 = (b0 + 1) < B; b1 = has2 ? b0 + 1 : b0;
            const f32x4* xv0 = (const f32x4*)(x + (size_t)b0 * D0);
            const f32x4* xv1 = (const f32x4*)(x + (size_t)b1 * D0);
            #pragma unroll
            for (int k = 0; k < 4; ++k) xa[k] = xv0[k * 64 + lane];
            #pragma unroll
            for (int k = 0; k < 4; ++k) xb[k] = xv1[k * 64 + lane];
        }

        // fp32 LIF state (reference dtype; spike margins ~4x threshold, and the
        // saturated fixed point a=1, v=0 is exact in fp32).
        float v0a = 0.f, a0a = 0.f, v1a = 0.f, a1a = 0.f;
        float v0b = 0.f, a0b = 0.f, v1b = 0.f, a1b = 0.f;

        for (int t = 0; t < TS; ++t) {
            const float tf = (float)t;
            const float a0a_s = a0a, a1a_s = a1a, a0b_s = a0b, a1b_s = a1b;

            // layer 0 both rows: cur0 = 2*mean|x - a0*s0| = S/512
            const float fa = a0a, fb = a0b;
            float pa0 = 0.f, pa1 = 0.f, pa2 = 0.f, pa3 = 0.f;
            float pb0 = 0.f, pb1 = 0.f, pb2 = 0.f, pb3 = 0.f;
            #pragma unroll
            for (int k = 0; k < 4; ++k) {
                pa0 += fabsf(fmaf(-fa, s0k[k].x, xa[k].x));
                pa1 += fabsf(fmaf(-fa, s0k[k].y, xa[k].y));
                pa2 += fabsf(fmaf(-fa, s0k[k].z, xa[k].z));
                pa3 += fabsf(fmaf(-fa, s0k[k].w, xa[k].w));
                pb0 += fabsf(fmaf(-fb, s0k[k].x, xb[k].x));
                pb1 += fabsf(fmaf(-fb, s0k[k].y, xb[k].y));
                pb2 += fabsf(fmaf(-fb, s0k[k].z, xb[k].z));
                pb3 += fabsf(fmaf(-fb, s0k[k].w, xb[k].w));
            }
            float ra = (pa0 + pa1) + (pa2 + pa3);
            float rb = (pb0 + pb1) + (pb2 + pb3);
            #pragma unroll
            for (int off = 32; off >= 1; off >>= 1) {
                ra += __shfl_xor(ra, off, 64);
                rb += __shfl_xor(rb, off, 64);
            }
            v0a = 0.5f * v0a + ra * (1.0f / 512.0f);
            v0b = 0.5f * v0b + rb * (1.0f / 512.0f);
            const float sp0a = (v0a >= 1.0f) ? 1.0f : 0.0f;
            const float sp0b = (v0b >= 1.0f) ? 1.0f : 0.0f;
            v0a = (v0a >= 1.0f) ? 0.0f : v0a;
            v0b = (v0b >= 1.0f) ? 0.0f : v0b;
            a0a = (a0a * tf + sp0a) / (tf + 1.0f);
            a0b = (a0b * tf + sp0b) / (tf + 1.0f);

            // layer 1 both rows: cur1 = 2*mean|a0_new - a1*s1| = S/256
            const float ga = a1a, gb = a1b;
            const float na = a0a, nb = a0b;
            float qa0 = 0.f, qa1 = 0.f, qb0 = 0.f, qb1 = 0.f;
            #pragma unroll
            for (int k = 0; k < 2; ++k) {
                qa0 += fabsf(fmaf(-ga, s1k[k].x, na)) + fabsf(fmaf(-ga, s1k[k].z, na));
                qa1 += fabsf(fmaf(-ga, s1k[k].y, na)) + fabsf(fmaf(-ga, s1k[k].w, na));
                qb0 += fabsf(fmaf(-gb, s1k[k].x, nb)) + fabsf(fmaf(-gb, s1k[k].z, nb));
                qb1 += fabsf(fmaf(-gb, s1k[k].y, nb)) + fabsf(fmaf(-gb, s1k[k].w, nb));
            }
            float ta = qa0 + qa1;
            float tb = qb0 + qb1;
            #pragma unroll
            for (int off = 32; off >= 1; off >>= 1) {
                ta += __shfl_xor(ta, off, 64);
                tb += __shfl_xor(tb, off, 64);
            }
            v1a = 0.5f * v1a + ta * (1.0f / 256.0f);
            v1b = 0.5f * v1b + tb * (1.0f / 256.0f);
            const float sp1a = (v1a >= 1.0f) ? 1.0f : 0.0f;
            const float sp1b = (v1b >= 1.0f) ? 1.0f : 0.0f;
            v1a = (v1a >= 1.0f) ? 0.0f : v1a;
            v1b = (v1b >= 1.0f) ? 0.0f : v1b;
            a1a = (a1a * tf + sp1a) / (tf + 1.0f);
            a1b = (a1b * tf + sp1b) / (tf + 1.0f);

            // exact fixed point: a==1 entering the step + spike this step =>
            // all future steps are bit-identical ((1*t+1)/(t+1)==1 exactly).
            const bool doneA = (a0a_s == 1.0f) && (sp0a == 1.0f) && (a1a_s == 1.0f) && (sp1a == 1.0f);
            const bool doneB = (a0b_s == 1.0f) && (sp0b == 1.0f) && (a1b_s == 1.0f) && (sp1b == 1.0f);
            if (doneA && (doneB || !has2)) break;
        }

        // broadcast result across 256 output features; one f32x4 per lane
        {
            f32x4 rv; rv.x = a1a; rv.y = a1a; rv.z = a1a; rv.w = a1a;
            f32x4* ov = (f32x4*)(out + (size_t)b0 * D2);
            __builtin_nontemporal_store(rv, &ov[lane]);
        }
        if (has2) {
            f32x4 rv; rv.x = a1b; rv.y = a1b; rv.z = a1b; rv.w = a1b;
            f32x4* ov = (f32x4*)(out + (size_t)b1 * D2);
            __builtin_nontemporal_store(rv, &ov[lane]);
        }
    }
}

extern "C" void kernel_launch(void* const* d_in, const int* in_sizes, int n_in,
                              void* d_out, int out_size, void* d_ws, size_t ws_size,
                              hipStream_t stream) {
    const float* x  = (const float*)d_in[0];
    const float* W0 = (const float*)d_in[1];
    const float* W1 = (const float*)d_in[2];
    const int*   ts = (const int*)d_in[3];
    float* out = (float*)d_out;
    float* s   = (float*)d_ws;   // s[0..1024) = rowsum(W0), s[1024..1536) = rowsum(W1)
    int B = in_sizes[0] / D0;

    // Cooperative launch: clamp grid to guaranteed co-residency.
    int maxb = 0;
    (void)hipOccupancyMaxActiveBlocksPerMultiprocessor(&maxb, snn_fused, 256, 0);
    if (maxb < 1) maxb = 1;
    int grid = maxb * 256;            // 256 CUs on MI355X
    if (grid > 1024) grid = 1024;     // 1024 blocks x 4 waves = 4096 waves is plenty

    void* args[] = { (void*)&x, (void*)&W0, (void*)&W1, (void*)&ts,
                     (void*)&out, (void*)&s, (void*)&B };
    (void)hipLaunchCooperativeKernel((const void*)snn_fused,
                                     dim3(grid), dim3(256), args, 0, stream);
}

// Round 6
// 118.208 us; speedup vs baseline: 1.3206x; 1.3206x over previous
//
#include <hip/hip_runtime.h>
#include <hip/hip_cooperative_groups.h>

namespace cg = cooperative_groups;

#define D0 1024
#define D1 512
#define D2 256
#define NROWSUM (D0 + D1)

typedef float f32x4 __attribute__((ext_vector_type(4)));

// Single fused cooperative kernel.
// Phase 1: rowsums of W0 (1024x512) and W1 (512x256) -> s[1536].
//   (pred[b,i] = avg[b]*rowsum(W)[i] because cur is a [B,1] broadcast, so the
//    per-layer state collapses to scalars (v, avg) per batch row.)
// Then each wave ISSUES its first x-row-pair loads (they stay in flight across
// the grid barrier — vmcnt only drains at use), grid.sync(), phase 2 iterates
// the scalar LIF dynamics per batch row with the exact-fixed-point early break.
//
// NOTE: no min-waves arg in launch_bounds — R5's (256,4) capped VGPRs at 64 and
// spilled xa/xb/s0k to scratch (WRITE_SIZE 117 MB vs 34 MB algorithmic, 4.3x
// slowdown). This kernel wants ~100 VGPRs; occupancy is set by the grid query.
__global__ __launch_bounds__(256) void snn_fused(
    const float* __restrict__ x,
    const float* __restrict__ W0,
    const float* __restrict__ W1,
    const int*   __restrict__ ts_ptr,
    float* __restrict__ out,
    float* __restrict__ s,
    int B)
{
    const int lane = threadIdx.x & 63;
    const int wid  = threadIdx.x >> 6;
    const int gw   = blockIdx.x * 4 + wid;   // global wave id
    const int nw   = gridDim.x * 4;          // total waves

    // ---------------- phase 1: rowsums ----------------
    for (int row = gw; row < NROWSUM; row += nw) {
        const f32x4* base; int n4;
        if (row < D0) { base = (const f32x4*)(W0 + (size_t)row * D1);        n4 = D1 / 4; }
        else          { base = (const f32x4*)(W1 + (size_t)(row - D0) * D2); n4 = D2 / 4; }
        double acc = 0.0;
        for (int j = lane; j < n4; j += 64) {
            const f32x4 v = base[j];
            acc += ((double)v.x + (double)v.y) + ((double)v.z + (double)v.w);
        }
        #pragma unroll
        for (int off = 32; off >= 1; off >>= 1) acc += __shfl_xor(acc, off, 64);
        if (lane == 0) s[row] = (float)acc;
    }

    // ------- prefetch first x pair; loads complete across the barrier -------
    const int P = (B + 1) >> 1;   // row pairs
    const int pair0 = gw;
    f32x4 xa[4], xb[4];
    int b0 = 0, b1 = 0; bool has2 = false;
    if (pair0 < P) {
        b0 = pair0 * 2; has2 = (b0 + 1) < B; b1 = has2 ? b0 + 1 : b0;
        const f32x4* xv0 = (const f32x4*)(x + (size_t)b0 * D0);
        const f32x4* xv1 = (const f32x4*)(x + (size_t)b1 * D0);
        #pragma unroll
        for (int k = 0; k < 4; ++k) xa[k] = xv0[k * 64 + lane];
        #pragma unroll
        for (int k = 0; k < 4; ++k) xb[k] = xv1[k * 64 + lane];
    }

    __threadfence();            // device-scope release of s
    cg::this_grid().sync();     // all rowsums visible grid-wide

    // ---------------- phase 2: LIF iteration ----------------
    const f32x4* sv = (const f32x4*)s;
    f32x4 s0k[4], s1k[2];
    #pragma unroll
    for (int k = 0; k < 4; ++k) s0k[k] = sv[k * 64 + lane];
    #pragma unroll
    for (int k = 0; k < 2; ++k) s1k[k] = sv[D0 / 4 + k * 64 + lane];
    const int TS = *ts_ptr;

    for (int pair = pair0; pair < P; pair += nw) {
        if (pair != pair0) {
            b0 = pair * 2; has2 = (b0 + 1) < B; b1 = has2 ? b0 + 1 : b0;
            const f32x4* xv0 = (const f32x4*)(x + (size_t)b0 * D0);
            const f32x4* xv1 = (const f32x4*)(x + (size_t)b1 * D0);
            #pragma unroll
            for (int k = 0; k < 4; ++k) xa[k] = xv0[k * 64 + lane];
            #pragma unroll
            for (int k = 0; k < 4; ++k) xb[k] = xv1[k * 64 + lane];
        }

        // fp32 LIF state (reference dtype; spike margins ~4x threshold, and the
        // saturated fixed point a=1, v=0 is exact in fp32).
        float v0a = 0.f, a0a = 0.f, v1a = 0.f, a1a = 0.f;
        float v0b = 0.f, a0b = 0.f, v1b = 0.f, a1b = 0.f;

        for (int t = 0; t < TS; ++t) {
            const float tf = (float)t;
            const float a0a_s = a0a, a1a_s = a1a, a0b_s = a0b, a1b_s = a1b;

            // layer 0 both rows: cur0 = 2*mean|x - a0*s0| = S/512
            const float fa = a0a, fb = a0b;
            float pa0 = 0.f, pa1 = 0.f, pa2 = 0.f, pa3 = 0.f;
            float pb0 = 0.f, pb1 = 0.f, pb2 = 0.f, pb3 = 0.f;
            #pragma unroll
            for (int k = 0; k < 4; ++k) {
                pa0 += fabsf(fmaf(-fa, s0k[k].x, xa[k].x));
                pa1 += fabsf(fmaf(-fa, s0k[k].y, xa[k].y));
                pa2 += fabsf(fmaf(-fa, s0k[k].z, xa[k].z));
                pa3 += fabsf(fmaf(-fa, s0k[k].w, xa[k].w));
                pb0 += fabsf(fmaf(-fb, s0k[k].x, xb[k].x));
                pb1 += fabsf(fmaf(-fb, s0k[k].y, xb[k].y));
                pb2 += fabsf(fmaf(-fb, s0k[k].z, xb[k].z));
                pb3 += fabsf(fmaf(-fb, s0k[k].w, xb[k].w));
            }
            float ra = (pa0 + pa1) + (pa2 + pa3);
            float rb = (pb0 + pb1) + (pb2 + pb3);
            #pragma unroll
            for (int off = 32; off >= 1; off >>= 1) {
                ra += __shfl_xor(ra, off, 64);
                rb += __shfl_xor(rb, off, 64);
            }
            v0a = 0.5f * v0a + ra * (1.0f / 512.0f);
            v0b = 0.5f * v0b + rb * (1.0f / 512.0f);
            const float sp0a = (v0a >= 1.0f) ? 1.0f : 0.0f;
            const float sp0b = (v0b >= 1.0f) ? 1.0f : 0.0f;
            v0a = (v0a >= 1.0f) ? 0.0f : v0a;
            v0b = (v0b >= 1.0f) ? 0.0f : v0b;
            a0a = (a0a * tf + sp0a) / (tf + 1.0f);
            a0b = (a0b * tf + sp0b) / (tf + 1.0f);

            // layer 1 both rows: cur1 = 2*mean|a0_new - a1*s1| = S/256
            const float ga = a1a, gb = a1b;
            const float na = a0a, nb = a0b;
            float qa0 = 0.f, qa1 = 0.f, qb0 = 0.f, qb1 = 0.f;
            #pragma unroll
            for (int k = 0; k < 2; ++k) {
                qa0 += fabsf(fmaf(-ga, s1k[k].x, na)) + fabsf(fmaf(-ga, s1k[k].z, na));
                qa1 += fabsf(fmaf(-ga, s1k[k].y, na)) + fabsf(fmaf(-ga, s1k[k].w, na));
                qb0 += fabsf(fmaf(-gb, s1k[k].x, nb)) + fabsf(fmaf(-gb, s1k[k].z, nb));
                qb1 += fabsf(fmaf(-gb, s1k[k].y, nb)) + fabsf(fmaf(-gb, s1k[k].w, nb));
            }
            float ta = qa0 + qa1;
            float tb = qb0 + qb1;
            #pragma unroll
            for (int off = 32; off >= 1; off >>= 1) {
                ta += __shfl_xor(ta, off, 64);
                tb += __shfl_xor(tb, off, 64);
            }
            v1a = 0.5f * v1a + ta * (1.0f / 256.0f);
            v1b = 0.5f * v1b + tb * (1.0f / 256.0f);
            const float sp1a = (v1a >= 1.0f) ? 1.0f : 0.0f;
            const float sp1b = (v1b >= 1.0f) ? 1.0f : 0.0f;
            v1a = (v1a >= 1.0f) ? 0.0f : v1a;
            v1b = (v1b >= 1.0f) ? 0.0f : v1b;
            a1a = (a1a * tf + sp1a) / (tf + 1.0f);
            a1b = (a1b * tf + sp1b) / (tf + 1.0f);

            // exact fixed point: a==1 entering the step + spike this step =>
            // all future steps are bit-identical ((1*t+1)/(t+1)==1 exactly).
            const bool doneA = (a0a_s == 1.0f) && (sp0a == 1.0f) && (a1a_s == 1.0f) && (sp1a == 1.0f);
            const bool doneB = (a0b_s == 1.0f) && (sp0b == 1.0f) && (a1b_s == 1.0f) && (sp1b == 1.0f);
            if (doneA && (doneB || !has2)) break;
        }

        // broadcast result across 256 output features; one f32x4 per lane
        {
            f32x4 rv; rv.x = a1a; rv.y = a1a; rv.z = a1a; rv.w = a1a;
            f32x4* ov = (f32x4*)(out + (size_t)b0 * D2);
            __builtin_nontemporal_store(rv, &ov[lane]);
        }
        if (has2) {
            f32x4 rv; rv.x = a1b; rv.y = a1b; rv.z = a1b; rv.w = a1b;
            f32x4* ov = (f32x4*)(out + (size_t)b1 * D2);
            __builtin_nontemporal_store(rv, &ov[lane]);
        }
    }
}

extern "C" void kernel_launch(void* const* d_in, const int* in_sizes, int n_in,
                              void* d_out, int out_size, void* d_ws, size_t ws_size,
                              hipStream_t stream) {
    const float* x  = (const float*)d_in[0];
    const float* W0 = (const float*)d_in[1];
    const float* W1 = (const float*)d_in[2];
    const int*   ts = (const int*)d_in[3];
    float* out = (float*)d_out;
    float* s   = (float*)d_ws;   // s[0..1024) = rowsum(W0), s[1024..1536) = rowsum(W1)
    int B = in_sizes[0] / D0;

    // Cooperative launch: clamp grid to guaranteed co-residency.
    int maxb = 0;
    (void)hipOccupancyMaxActiveBlocksPerMultiprocessor(&maxb, snn_fused, 256, 0);
    if (maxb < 1) maxb = 1;
    int grid = maxb * 256;            // 256 CUs on MI355X
    if (grid > 2048) grid = 2048;

    void* args[] = { (void*)&x, (void*)&W0, (void*)&W1, (void*)&ts,
                     (void*)&out, (void*)&s, (void*)&B };
    (void)hipLaunchCooperativeKernel((const void*)snn_fused,
                                     dim3(grid), dim3(256), args, 0, stream);
}

// Round 7
// 111.956 us; speedup vs baseline: 1.3944x; 1.0558x over previous
//
#include <hip/hip_runtime.h>

#define D0 1024
#define D1 512
#define D2 256
#define NROWSUM (D0 + D1)
#define NBLOCKS 256
#define NTHREADS 1024
#define WAVES_PER_BLOCK (NTHREADS / 64)

typedef float f32x4 __attribute__((ext_vector_type(4)));

// Single fused kernel, NO grid sync (R6 post-mortem: cg grid.sync with 2048
// blocks cost ~100+ us). Instead each block redundantly computes all 1536
// rowsums into its own LDS: W is 2.5 MB and lives in each XCD's 4 MB L2, so
// the 256x redundancy is 640 MB of L2-hit traffic (~23 us aggregate at
// 34.5 TB/s), fully overlapped with the x HBM/L3 stream.
//
// Math collapse (verified absmax=0.0 in R1-R6): cur is a [B,1] broadcast and
// state starts at 0, so per-layer state is a scalar pair (v, avg) per batch
// row and pred[b,i] = avg[b] * rowsum(W)[i].
__global__ __launch_bounds__(NTHREADS) void snn_fused(
    const float* __restrict__ x,
    const float* __restrict__ W0,
    const float* __restrict__ W1,
    const int*   __restrict__ ts_ptr,
    float* __restrict__ out,
    int B)
{
    __shared__ __align__(16) float s_lds[NROWSUM];

    const int lane = threadIdx.x & 63;
    const int wv   = threadIdx.x >> 6;          // 0..15

    // ---------------- phase 1: per-block rowsums into LDS ----------------
    for (int row = wv; row < NROWSUM; row += WAVES_PER_BLOCK) {
        const f32x4* base; int n4;
        if (row < D0) { base = (const f32x4*)(W0 + (size_t)row * D1);        n4 = D1 / 4; }
        else          { base = (const f32x4*)(W1 + (size_t)(row - D0) * D2); n4 = D2 / 4; }
        double acc = 0.0;
        for (int j = lane; j < n4; j += 64) {
            const f32x4 v = base[j];
            acc += ((double)v.x + (double)v.y) + ((double)v.z + (double)v.w);
        }
        #pragma unroll
        for (int off = 32; off >= 1; off >>= 1) acc += __shfl_xor(acc, off, 64);
        if (lane == 0) s_lds[row] = (float)acc;
    }
    __syncthreads();

    // ---------------- phase 2: LIF over batch-row pairs ----------------
    const f32x4* sv = (const f32x4*)s_lds;
    f32x4 s0k[4], s1k[2];
    #pragma unroll
    for (int k = 0; k < 4; ++k) s0k[k] = sv[k * 64 + lane];
    #pragma unroll
    for (int k = 0; k < 2; ++k) s1k[k] = sv[D0 / 4 + k * 64 + lane];
    const int TS = *ts_ptr;

    const int P  = (B + 1) >> 1;                       // row pairs
    const int gw = blockIdx.x * WAVES_PER_BLOCK + wv;  // global wave id
    const int nw = gridDim.x * WAVES_PER_BLOCK;        // total waves

    for (int pair = gw; pair < P; pair += nw) {
        const int  b0   = pair * 2;
        const bool has2 = (b0 + 1) < B;
        const int  b1   = has2 ? b0 + 1 : b0;
        const f32x4* xv0 = (const f32x4*)(x + (size_t)b0 * D0);
        const f32x4* xv1 = (const f32x4*)(x + (size_t)b1 * D0);
        f32x4 xa[4], xb[4];
        #pragma unroll
        for (int k = 0; k < 4; ++k) xa[k] = xv0[k * 64 + lane];
        #pragma unroll
        for (int k = 0; k < 4; ++k) xb[k] = xv1[k * 64 + lane];

        // fp32 LIF state (spike margins ~4x threshold; saturated fixed point
        // a=1, v=0 is exact in fp32 — verified absmax=0.0 in R5/R6).
        float v0a = 0.f, a0a = 0.f, v1a = 0.f, a1a = 0.f;
        float v0b = 0.f, a0b = 0.f, v1b = 0.f, a1b = 0.f;

        for (int t = 0; t < TS; ++t) {
            const float tf = (float)t;
            const float a0a_s = a0a, a1a_s = a1a, a0b_s = a0b, a1b_s = a1b;

            // layer 0 both rows: cur0 = 2*mean|x - a0*s0| = S/512
            const float fa = a0a, fb = a0b;
            float pa0 = 0.f, pa1 = 0.f, pa2 = 0.f, pa3 = 0.f;
            float pb0 = 0.f, pb1 = 0.f, pb2 = 0.f, pb3 = 0.f;
            #pragma unroll
            for (int k = 0; k < 4; ++k) {
                pa0 += fabsf(fmaf(-fa, s0k[k].x, xa[k].x));
                pa1 += fabsf(fmaf(-fa, s0k[k].y, xa[k].y));
                pa2 += fabsf(fmaf(-fa, s0k[k].z, xa[k].z));
                pa3 += fabsf(fmaf(-fa, s0k[k].w, xa[k].w));
                pb0 += fabsf(fmaf(-fb, s0k[k].x, xb[k].x));
                pb1 += fabsf(fmaf(-fb, s0k[k].y, xb[k].y));
                pb2 += fabsf(fmaf(-fb, s0k[k].z, xb[k].z));
                pb3 += fabsf(fmaf(-fb, s0k[k].w, xb[k].w));
            }
            float ra = (pa0 + pa1) + (pa2 + pa3);
            float rb = (pb0 + pb1) + (pb2 + pb3);
            #pragma unroll
            for (int off = 32; off >= 1; off >>= 1) {
                ra += __shfl_xor(ra, off, 64);
                rb += __shfl_xor(rb, off, 64);
            }
            v0a = 0.5f * v0a + ra * (1.0f / 512.0f);
            v0b = 0.5f * v0b + rb * (1.0f / 512.0f);
            const float sp0a = (v0a >= 1.0f) ? 1.0f : 0.0f;
            const float sp0b = (v0b >= 1.0f) ? 1.0f : 0.0f;
            v0a = (v0a >= 1.0f) ? 0.0f : v0a;
            v0b = (v0b >= 1.0f) ? 0.0f : v0b;
            a0a = (a0a * tf + sp0a) / (tf + 1.0f);
            a0b = (a0b * tf + sp0b) / (tf + 1.0f);

            // layer 1 both rows: cur1 = 2*mean|a0_new - a1*s1| = S/256
            const float ga = a1a, gb = a1b;
            const float na = a0a, nb = a0b;
            float qa0 = 0.f, qa1 = 0.f, qb0 = 0.f, qb1 = 0.f;
            #pragma unroll
            for (int k = 0; k < 2; ++k) {
                qa0 += fabsf(fmaf(-ga, s1k[k].x, na)) + fabsf(fmaf(-ga, s1k[k].z, na));
                qa1 += fabsf(fmaf(-ga, s1k[k].y, na)) + fabsf(fmaf(-ga, s1k[k].w, na));
                qb0 += fabsf(fmaf(-gb, s1k[k].x, nb)) + fabsf(fmaf(-gb, s1k[k].z, nb));
                qb1 += fabsf(fmaf(-gb, s1k[k].y, nb)) + fabsf(fmaf(-gb, s1k[k].w, nb));
            }
            float ta = qa0 + qa1;
            float tb = qb0 + qb1;
            #pragma unroll
            for (int off = 32; off >= 1; off >>= 1) {
                ta += __shfl_xor(ta, off, 64);
                tb += __shfl_xor(tb, off, 64);
            }
            v1a = 0.5f * v1a + ta * (1.0f / 256.0f);
            v1b = 0.5f * v1b + tb * (1.0f / 256.0f);
            const float sp1a = (v1a >= 1.0f) ? 1.0f : 0.0f;
            const float sp1b = (v1b >= 1.0f) ? 1.0f : 0.0f;
            v1a = (v1a >= 1.0f) ? 0.0f : v1a;
            v1b = (v1b >= 1.0f) ? 0.0f : v1b;
            a1a = (a1a * tf + sp1a) / (tf + 1.0f);
            a1b = (a1b * tf + sp1b) / (tf + 1.0f);

            // exact fixed point: a==1 entering the step + spike this step =>
            // all future steps are bit-identical ((1*t+1)/(t+1)==1 exactly).
            const bool doneA = (a0a_s == 1.0f) && (sp0a == 1.0f) && (a1a_s == 1.0f) && (sp1a == 1.0f);
            const bool doneB = (a0b_s == 1.0f) && (sp0b == 1.0f) && (a1b_s == 1.0f) && (sp1b == 1.0f);
            if (doneA && (doneB || !has2)) break;
        }

        // broadcast result across 256 output features; one f32x4 per lane
        {
            f32x4 rv; rv.x = a1a; rv.y = a1a; rv.z = a1a; rv.w = a1a;
            f32x4* ov = (f32x4*)(out + (size_t)b0 * D2);
            __builtin_nontemporal_store(rv, &ov[lane]);
        }
        if (has2) {
            f32x4 rv; rv.x = a1b; rv.y = a1b; rv.z = a1b; rv.w = a1b;
            f32x4* ov = (f32x4*)(out + (size_t)b1 * D2);
            __builtin_nontemporal_store(rv, &ov[lane]);
        }
    }
}

extern "C" void kernel_launch(void* const* d_in, const int* in_sizes, int n_in,
                              void* d_out, int out_size, void* d_ws, size_t ws_size,
                              hipStream_t stream) {
    const float* x  = (const float*)d_in[0];
    const float* W0 = (const float*)d_in[1];
    const float* W1 = (const float*)d_in[2];
    const int*   ts = (const int*)d_in[3];
    float* out = (float*)d_out;
    int B = in_sizes[0] / D0;

    snn_fused<<<NBLOCKS, NTHREADS, 0, stream>>>(x, W0, W1, ts, out, B);
}

// Round 8
// 35.294 us; speedup vs baseline: 4.4231x; 3.1721x over previous
//
#include <hip/hip_runtime.h>

#define D0 1024
#define D1 512
#define D2 256
#define NROWSUM (D0 + D1)

typedef float f32x4 __attribute__((ext_vector_type(4)));

// Kernel 1: row sums of W0 (1024x512) and W1 (512x256) -> s[1536].
// pred[b,i] = avg[b]*rowsum(W)[i] since cur is a [B,1] broadcast (state
// collapses to scalars per row). One wave per row, 256-thread blocks.
__global__ __launch_bounds__(256) void snn_rowsum(const float* __restrict__ W0,
                                                  const float* __restrict__ W1,
                                                  float* __restrict__ s) {
    const int lane = threadIdx.x & 63;
    const int wid  = threadIdx.x >> 6;
    const int row  = blockIdx.x * 4 + wid;
    if (row >= NROWSUM) return;
    const f32x4* base;
    int n4;
    if (row < D0) { base = (const f32x4*)(W0 + (size_t)row * D1);        n4 = D1 / 4; }
    else          { base = (const f32x4*)(W1 + (size_t)(row - D0) * D2); n4 = D2 / 4; }
    double acc = 0.0;
    for (int j = lane; j < n4; j += 64) {
        const f32x4 v = base[j];
        acc += ((double)v.x + (double)v.y) + ((double)v.z + (double)v.w);
    }
    #pragma unroll
    for (int off = 32; off >= 1; off >>= 1) acc += __shfl_xor(acc, off, 64);
    if (lane == 0) s[row] = (float)acc;
}

// Kernel 2: 2 batch rows per wave. FAST PATH: while a0,a1 stay in {0,1}
// (i.e. all-spike or no-spike history — always true for this data, margins
// ~4x threshold), the currents take only table values:
//   cur0(a0=0) = G0/512,  cur0(a0=1) = G1/512   (G0=Sum|x|, G1=Sum|x-s0|)
//   cur1(0,0)=0, cur1(1,0)=2, cur1(0,1)=2*mean|s1|, cur1(1,1)=2*mean|1-s1|
// so the t-loop is pure scalar — ONE feature pass + ONE 4-sum butterfly per
// pair (R7 lesson: DS-pipe shuffles were the hidden serial cost).
// GUARD: if any a leaves {0,1}, rerun the general per-t path from t=0 (x is
// still in registers) — bitwise-correct for arbitrary inputs, never taken here.
__global__ __launch_bounds__(256) void snn_main(const float* __restrict__ x,
                                                const float* __restrict__ s,
                                                const int* __restrict__ ts_ptr,
                                                float* __restrict__ out,
                                                int B) {
    const int lane = threadIdx.x & 63;
    const int wid  = threadIdx.x >> 6;
    const int pair = blockIdx.x * 4 + wid;
    const int P    = (B + 1) >> 1;
    if (pair >= P) return;
    const int  b0   = pair * 2;
    const bool has2 = (b0 + 1) < B;
    const int  b1   = has2 ? b0 + 1 : b0;
    const int  TS   = *ts_ptr;

    // s fragments (L2/L3-resident)
    const f32x4* sv = (const f32x4*)s;
    f32x4 s0k[4], s1k[2];
    #pragma unroll
    for (int k = 0; k < 4; ++k) s0k[k] = sv[k * 64 + lane];
    #pragma unroll
    for (int k = 0; k < 2; ++k) s1k[k] = sv[D0 / 4 + k * 64 + lane];

    // per-wave layer-1 constants: 2*mean|s1| and 2*mean|1-s1| (512 terms /256)
    float u0 = 0.f, u1 = 0.f;
    #pragma unroll
    for (int k = 0; k < 2; ++k) {
        u0 += fabsf(s1k[k].x) + fabsf(s1k[k].y) + fabsf(s1k[k].z) + fabsf(s1k[k].w);
        u1 += fabsf(1.0f - s1k[k].x) + fabsf(1.0f - s1k[k].y)
            + fabsf(1.0f - s1k[k].z) + fabsf(1.0f - s1k[k].w);
    }
    #pragma unroll
    for (int off = 32; off >= 1; off >>= 1) {
        u0 += __shfl_xor(u0, off, 64);
        u1 += __shfl_xor(u1, off, 64);
    }
    const float cur1_01 = u0 * (1.0f / 256.0f);   // a0=0, a1=1
    const float cur1_11 = u1 * (1.0f / 256.0f);   // a0=1, a1=1

    // load x pair
    const f32x4* xv0 = (const f32x4*)(x + (size_t)b0 * D0);
    const f32x4* xv1 = (const f32x4*)(x + (size_t)b1 * D0);
    f32x4 xa[4], xb[4];
    #pragma unroll
    for (int k = 0; k < 4; ++k) xa[k] = xv0[k * 64 + lane];
    #pragma unroll
    for (int k = 0; k < 4; ++k) xb[k] = xv1[k * 64 + lane];

    // one feature pass: G0=Sum|x|, G1=Sum|x-s0| for both rows
    float ga0 = 0.f, ga1 = 0.f, gb0 = 0.f, gb1 = 0.f;
    #pragma unroll
    for (int k = 0; k < 4; ++k) {
        ga0 += fabsf(xa[k].x) + fabsf(xa[k].y) + fabsf(xa[k].z) + fabsf(xa[k].w);
        gb0 += fabsf(xb[k].x) + fabsf(xb[k].y) + fabsf(xb[k].z) + fabsf(xb[k].w);
        ga1 += fabsf(xa[k].x - s0k[k].x) + fabsf(xa[k].y - s0k[k].y)
             + fabsf(xa[k].z - s0k[k].z) + fabsf(xa[k].w - s0k[k].w);
        gb1 += fabsf(xb[k].x - s0k[k].x) + fabsf(xb[k].y - s0k[k].y)
             + fabsf(xb[k].z - s0k[k].z) + fabsf(xb[k].w - s0k[k].w);
    }
    #pragma unroll
    for (int off = 32; off >= 1; off >>= 1) {
        ga0 += __shfl_xor(ga0, off, 64);
        ga1 += __shfl_xor(ga1, off, 64);
        gb0 += __shfl_xor(gb0, off, 64);
        gb1 += __shfl_xor(gb1, off, 64);
    }
    const float c0a0 = ga0 * (1.0f / 512.0f), c0a1 = ga1 * (1.0f / 512.0f);
    const float c0b0 = gb0 * (1.0f / 512.0f), c0b1 = gb1 * (1.0f / 512.0f);

    // ---------------- fast scalar t-loop ----------------
    float v0a = 0.f, a0a = 0.f, v1a = 0.f, a1a = 0.f;
    float v0b = 0.f, a0b = 0.f, v1b = 0.f, a1b = 0.f;
    bool fallback = false;

    for (int t = 0; t < TS; ++t) {
        const bool okA = (a0a == 0.f || a0a == 1.f) && (a1a == 0.f || a1a == 1.f);
        const bool okB = (a0b == 0.f || a0b == 1.f) && (a1b == 0.f || a1b == 1.f);
        if (!(okA && okB)) { fallback = true; break; }
        const float tf = (float)t;
        const float a0a_s = a0a, a1a_s = a1a, a0b_s = a0b, a1b_s = a1b;

        // layer 0
        const float cur0a = (a0a == 1.f) ? c0a1 : c0a0;
        const float cur0b = (a0b == 1.f) ? c0b1 : c0b0;
        v0a = 0.5f * v0a + cur0a;
        v0b = 0.5f * v0b + cur0b;
        const float sp0a = (v0a >= 1.0f) ? 1.0f : 0.0f;
        const float sp0b = (v0b >= 1.0f) ? 1.0f : 0.0f;
        v0a = (v0a >= 1.0f) ? 0.0f : v0a;
        v0b = (v0b >= 1.0f) ? 0.0f : v0b;
        a0a = (a0a * tf + sp0a) / (tf + 1.0f);
        a0b = (a0b * tf + sp0b) / (tf + 1.0f);

        // layer 1 (uses UPDATED a0; a0 may now be fractional — but then the
        // table lookup below would be invalid, so guard on updated a0 too)
        if (!((a0a == 0.f || a0a == 1.f) && (a0b == 0.f || a0b == 1.f))) {
            // undo nothing — rerun everything in the general path
            fallback = true; break;
        }
        const float cur1a = (a0a == 1.f) ? ((a1a == 1.f) ? cur1_11 : 2.0f)
                                         : ((a1a == 1.f) ? cur1_01 : 0.0f);
        const float cur1b = (a0b == 1.f) ? ((a1b == 1.f) ? cur1_11 : 2.0f)
                                         : ((a1b == 1.f) ? cur1_01 : 0.0f);
        v1a = 0.5f * v1a + cur1a;
        v1b = 0.5f * v1b + cur1b;
        const float sp1a = (v1a >= 1.0f) ? 1.0f : 0.0f;
        const float sp1b = (v1b >= 1.0f) ? 1.0f : 0.0f;
        v1a = (v1a >= 1.0f) ? 0.0f : v1a;
        v1b = (v1b >= 1.0f) ? 0.0f : v1b;
        a1a = (a1a * tf + sp1a) / (tf + 1.0f);
        a1b = (a1b * tf + sp1b) / (tf + 1.0f);

        // exact fixed point: a==1 entering + spike now => future steps identical
        const bool doneA = (a0a_s == 1.0f) && (sp0a == 1.0f) && (a1a_s == 1.0f) && (sp1a == 1.0f);
        const bool doneB = (a0b_s == 1.0f) && (sp0b == 1.0f) && (a1b_s == 1.0f) && (sp1b == 1.0f);
        if (doneA && (doneB || !has2)) break;
    }

    // ---------------- general fallback (never taken for this data) ----------
    if (fallback) {
        v0a = 0.f; a0a = 0.f; v1a = 0.f; a1a = 0.f;
        v0b = 0.f; a0b = 0.f; v1b = 0.f; a1b = 0.f;
        for (int t = 0; t < TS; ++t) {
            const float tf = (float)t;
            const float fa = a0a, fb = a0b;
            float pa = 0.f, pb = 0.f;
            #pragma unroll
            for (int k = 0; k < 4; ++k) {
                pa += fabsf(fmaf(-fa, s0k[k].x, xa[k].x)) + fabsf(fmaf(-fa, s0k[k].y, xa[k].y))
                    + fabsf(fmaf(-fa, s0k[k].z, xa[k].z)) + fabsf(fmaf(-fa, s0k[k].w, xa[k].w));
                pb += fabsf(fmaf(-fb, s0k[k].x, xb[k].x)) + fabsf(fmaf(-fb, s0k[k].y, xb[k].y))
                    + fabsf(fmaf(-fb, s0k[k].z, xb[k].z)) + fabsf(fmaf(-fb, s0k[k].w, xb[k].w));
            }
            #pragma unroll
            for (int off = 32; off >= 1; off >>= 1) {
                pa += __shfl_xor(pa, off, 64);
                pb += __shfl_xor(pb, off, 64);
            }
            v0a = 0.5f * v0a + pa * (1.0f / 512.0f);
            v0b = 0.5f * v0b + pb * (1.0f / 512.0f);
            const float sp0a = (v0a >= 1.0f) ? 1.0f : 0.0f;
            const float sp0b = (v0b >= 1.0f) ? 1.0f : 0.0f;
            v0a = (v0a >= 1.0f) ? 0.0f : v0a;
            v0b = (v0b >= 1.0f) ? 0.0f : v0b;
            a0a = (a0a * tf + sp0a) / (tf + 1.0f);
            a0b = (a0b * tf + sp0b) / (tf + 1.0f);

            const float ga = a1a, gb = a1b;
            const float na = a0a, nb = a0b;
            float qa = 0.f, qb = 0.f;
            #pragma unroll
            for (int k = 0; k < 2; ++k) {
                qa += fabsf(fmaf(-ga, s1k[k].x, na)) + fabsf(fmaf(-ga, s1k[k].y, na))
                    + fabsf(fmaf(-ga, s1k[k].z, na)) + fabsf(fmaf(-ga, s1k[k].w, na));
                qb += fabsf(fmaf(-gb, s1k[k].x, nb)) + fabsf(fmaf(-gb, s1k[k].y, nb))
                    + fabsf(fmaf(-gb, s1k[k].z, nb)) + fabsf(fmaf(-gb, s1k[k].w, nb));
            }
            #pragma unroll
            for (int off = 32; off >= 1; off >>= 1) {
                qa += __shfl_xor(qa, off, 64);
                qb += __shfl_xor(qb, off, 64);
            }
            v1a = 0.5f * v1a + qa * (1.0f / 256.0f);
            v1b = 0.5f * v1b + qb * (1.0f / 256.0f);
            const float sp1a = (v1a >= 1.0f) ? 1.0f : 0.0f;
            const float sp1b = (v1b >= 1.0f) ? 1.0f : 0.0f;
            v1a = (v1a >= 1.0f) ? 0.0f : v1a;
            v1b = (v1b >= 1.0f) ? 0.0f : v1b;
            a1a = (a1a * tf + sp1a) / (tf + 1.0f);
            a1b = (a1b * tf + sp1b) / (tf + 1.0f);
        }
    }

    // broadcast result across 256 output features; one f32x4 per lane
    {
        f32x4 rv; rv.x = a1a; rv.y = a1a; rv.z = a1a; rv.w = a1a;
        f32x4* ov = (f32x4*)(out + (size_t)b0 * D2);
        __builtin_nontemporal_store(rv, &ov[lane]);
    }
    if (has2) {
        f32x4 rv; rv.x = a1b; rv.y = a1b; rv.z = a1b; rv.w = a1b;
        f32x4* ov = (f32x4*)(out + (size_t)b1 * D2);
        __builtin_nontemporal_store(rv, &ov[lane]);
    }
}

extern "C" void kernel_launch(void* const* d_in, const int* in_sizes, int n_in,
                              void* d_out, int out_size, void* d_ws, size_t ws_size,
                              hipStream_t stream) {
    const float* x  = (const float*)d_in[0];
    const float* W0 = (const float*)d_in[1];
    const float* W1 = (const float*)d_in[2];
    const int*   ts = (const int*)d_in[3];
    float* out = (float*)d_out;
    float* s   = (float*)d_ws;   // s[0..1024) = rowsum(W0), s[1024..1536) = rowsum(W1)
    const int B = in_sizes[0] / D0;
    const int P = (B + 1) >> 1;

    snn_rowsum<<<(NROWSUM + 3) / 4, 256, 0, stream>>>(W0, W1, s);
    snn_main<<<(P + 3) / 4, 256, 0, stream>>>(x, s, ts, out, B);
}